// Round 4
// baseline (1720.824 us; speedup 1.0000x reference)
//
#include <hip/hip_runtime.h>
#include <cstdint>
#include <cstddef>

#define B_ 16
#define C_ 64
#define N_ 2048
#define K_ 20
#define TM2 128
#define L 7
#define CAND 24

// K1: replicate np.sum(xt*xt, axis=-1) in f32: elementwise rounded products,
// then numpy pairwise_sum for n=64: 8 accumulators + fixed combine tree.
__global__ __launch_bounds__(256) void k_sq(const float* __restrict__ x,
                                            float* __restrict__ sqf) {
    int i = blockIdx.x * 256 + threadIdx.x;   // 0..B_*N_-1
    int b = i >> 11, n = i & (N_ - 1);
    const float* xb = x + (size_t)b * C_ * N_ + n;
    float p[C_];
#pragma unroll
    for (int c = 0; c < C_; ++c) {
        float v = xb[(size_t)c * N_];
        p[c] = __fmul_rn(v, v);
    }
    float r[8];
#pragma unroll
    for (int k = 0; k < 8; ++k) r[k] = p[k];
#pragma unroll
    for (int ii = 8; ii < 64; ii += 8) {
#pragma unroll
        for (int k = 0; k < 8; ++k) r[k] = __fadd_rn(r[k], p[ii + k]);
    }
    float s0 = __fadd_rn(__fadd_rn(r[0], r[1]), __fadd_rn(r[2], r[3]));
    float s1 = __fadd_rn(__fadd_rn(r[4], r[5]), __fadd_rn(r[6], r[7]));
    sqf[i] = __fadd_rn(s0, s1);
}

// K3: Yt[b][m][o] = sum_c (W[o][c] - W[o][64+c]) * x[b][c][m]
__global__ __launch_bounds__(256) void k_y(const float* __restrict__ x,
                                           const float* __restrict__ W,
                                           float* __restrict__ Yt) {
    __shared__ float Al[C_ * 64];  // [c][o]
    __shared__ float xl[C_ * 64];  // [c][m]
    int tid = threadIdx.x;
    int bid = blockIdx.x;
    int b = bid >> 5;              // 32 m-tiles per batch
    int m0 = (bid & 31) * 64;
    {
        int o = tid & 63, cb = tid >> 6;
#pragma unroll
        for (int j = 0; j < 16; ++j) {
            int c = cb * 16 + j;
            Al[c * 64 + o] = W[o * 128 + c] - W[o * 128 + 64 + c];
            xl[c * 64 + o] = x[((size_t)b * C_ + c) * N_ + m0 + o];
        }
    }
    __syncthreads();
    int ml = tid & 63, og = tid >> 6;
    float acc[16];
#pragma unroll
    for (int j = 0; j < 16; ++j) acc[j] = 0.f;
#pragma unroll 4
    for (int c = 0; c < C_; ++c) {
        float xv = xl[c * 64 + ml];
        const float4* a4 = reinterpret_cast<const float4*>(&Al[c * 64 + og * 16]);
#pragma unroll
        for (int q = 0; q < 4; ++q) {
            float4 av = a4[q];
            acc[q * 4 + 0] = fmaf(av.x, xv, acc[q * 4 + 0]);
            acc[q * 4 + 1] = fmaf(av.y, xv, acc[q * 4 + 1]);
            acc[q * 4 + 2] = fmaf(av.z, xv, acc[q * 4 + 2]);
            acc[q * 4 + 3] = fmaf(av.w, xv, acc[q * 4 + 3]);
        }
    }
    float* yp = Yt + ((size_t)b * N_ + m0 + ml) * C_ + og * 16;
#pragma unroll
    for (int q = 0; q < 4; ++q) {
        reinterpret_cast<float4*>(yp)[q] =
            make_float4(acc[q * 4 + 0], acc[q * 4 + 1], acc[q * 4 + 2], acc[q * 4 + 3]);
    }
}

// K2a: fast tiled distance pass + per-lane top-L + wave extraction of CAND
// candidates per row. Fast f32/FMA values only NOMINATE; exact order fixed in
// k_rescore. Block: 4 waves x 8 rows = 32 rows; m staged in LDS tiles of 128.
__global__ __launch_bounds__(256) void k_dist(const float* __restrict__ x,
                                              const float* __restrict__ sqf,
                                              unsigned* __restrict__ cand) {
    __shared__ float xt[TM2][68];     // [m][c], stride 17 b128-units: conflict-free
    __shared__ float rowsl[32][68];
    __shared__ float sqm[TM2];
    __shared__ float rsq[32];
    int tid = threadIdx.x;
    int w = tid >> 6, lane = tid & 63;
    int bid = blockIdx.x;
    int b = bid >> 6;                 // 64 blocks per batch
    int n0 = (bid & 63) * 32;
    const float* xb = x + (size_t)b * C_ * N_;

    {   // stage the 32 row vectors once
        int i = tid & 31, cb2 = tid >> 5;
#pragma unroll
        for (int j = 0; j < 8; ++j) {
            int c = cb2 * 8 + j;
            rowsl[i][c] = xb[(size_t)c * N_ + n0 + i];
        }
        if (tid < 32) rsq[tid] = sqf[b * N_ + n0 + tid];
    }

    // per-lane unsorted top-L per row, max-tracked (all indices compile-time)
    float ld[8][L], lmax[8];
    unsigned li[8][L];
#pragma unroll
    for (int r = 0; r < 8; ++r) {
        lmax[r] = 1e30f;
#pragma unroll
        for (int j = 0; j < L; ++j) { ld[r][j] = 1e30f; li[r][j] = 0u; }
    }

    for (int t = 0; t < N_ / TM2; ++t) {
        int m0 = t * TM2;
        __syncthreads();
        {   // stage m-tile: thread owns m=tid&127, half the c-range
            int u = tid >> 7, ml = tid & 127;
#pragma unroll
            for (int cb2 = 0; cb2 < 8; ++cb2) {
                int c = (u * 8 + cb2) * 4;
                float4 v;
                v.x = xb[(size_t)(c + 0) * N_ + m0 + ml];
                v.y = xb[(size_t)(c + 1) * N_ + m0 + ml];
                v.z = xb[(size_t)(c + 2) * N_ + m0 + ml];
                v.w = xb[(size_t)(c + 3) * N_ + m0 + ml];
                *reinterpret_cast<float4*>(&xt[ml][c]) = v;
            }
            if (tid < TM2) sqm[tid] = sqf[b * N_ + m0 + tid];
        }
        __syncthreads();

        float acc[8][2];
#pragma unroll
        for (int r = 0; r < 8; ++r) { acc[r][0] = 0.f; acc[r][1] = 0.f; }
#pragma unroll 2
        for (int cc = 0; cc < 16; ++cc) {
            float4 xv0 = *reinterpret_cast<const float4*>(&xt[lane][cc * 4]);
            float4 xv1 = *reinterpret_cast<const float4*>(&xt[64 + lane][cc * 4]);
#pragma unroll
            for (int r = 0; r < 8; ++r) {
                float4 rv = *reinterpret_cast<const float4*>(&rowsl[w * 8 + r][cc * 4]);
                acc[r][0] = fmaf(rv.x, xv0.x, acc[r][0]);
                acc[r][0] = fmaf(rv.y, xv0.y, acc[r][0]);
                acc[r][0] = fmaf(rv.z, xv0.z, acc[r][0]);
                acc[r][0] = fmaf(rv.w, xv0.w, acc[r][0]);
                acc[r][1] = fmaf(rv.x, xv1.x, acc[r][1]);
                acc[r][1] = fmaf(rv.y, xv1.y, acc[r][1]);
                acc[r][1] = fmaf(rv.z, xv1.z, acc[r][1]);
                acc[r][1] = fmaf(rv.w, xv1.w, acc[r][1]);
            }
        }
#pragma unroll
        for (int s = 0; s < 2; ++s) {
            float sm = sqm[s * 64 + lane];
            int m = m0 + s * 64 + lane;
#pragma unroll
            for (int r = 0; r < 8; ++r) {
                float d = (rsq[w * 8 + r] + sm) - 2.f * acc[r][s];
                if (d < lmax[r]) {
                    bool done = false;
#pragma unroll
                    for (int j = 0; j < L; ++j) {
                        bool hit = (!done) && (ld[r][j] == lmax[r]);
                        if (hit) { ld[r][j] = d; li[r][j] = (unsigned)m; done = true; }
                    }
                    float mx = ld[r][0];
#pragma unroll
                    for (int j = 1; j < L; ++j) mx = fmaxf(mx, ld[r][j]);
                    lmax[r] = mx;
                }
            }
        }
    }

    // extraction: CAND rounds of wave-min + knockout, per row
#pragma unroll 1
    for (int r = 0; r < 8; ++r) {
        size_t grow = (size_t)b * N_ + n0 + w * 8 + r;
#pragma unroll 1
        for (int it = 0; it < CAND; ++it) {
            float v = ld[r][0];
#pragma unroll
            for (int j = 1; j < L; ++j) v = fminf(v, ld[r][j]);
            float wv = v;
#pragma unroll
            for (int d2 = 1; d2 < 64; d2 <<= 1)
                wv = fminf(wv, __shfl_xor(wv, d2, 64));
            unsigned long long bal = __ballot(v == wv);
            int owner = __ffsll((unsigned long long)bal) - 1;
            if (lane == owner) {
                bool done = false;
                unsigned mi = 0;
#pragma unroll
                for (int j = 0; j < L; ++j) {
                    bool hit = (!done) && (ld[r][j] == wv);
                    if (hit) { mi = li[r][j]; ld[r][j] = 1e30f; done = true; }
                }
                cand[grow * CAND + it] = mi;
            }
        }
    }
}

// K2b: exact numpy-f32 rescore of CAND candidates per row + stable rank.
__global__ __launch_bounds__(256) void k_rescore(const float* __restrict__ x,
                                                 const float* __restrict__ sqf,
                                                 const unsigned* __restrict__ cand,
                                                 float* __restrict__ idxf) {
    int tid = threadIdx.x;
    int w = tid >> 6, lane = tid & 63;
    size_t grow = (size_t)blockIdx.x * 4 + w;   // 0..32767
    int b = (int)(grow >> 11), n = (int)(grow & (N_ - 1));
    const float* xb = x + (size_t)b * C_ * N_;
    float d = 0.f;
    unsigned m = 0xFFFFFFFFu;
    if (lane < CAND) {
        m = cand[grow * CAND + lane];
        float a = 0.f;
#pragma unroll 8
        for (int c = 0; c < C_; ++c)
            a = __fadd_rn(a, __fmul_rn(xb[(size_t)c * N_ + n], xb[(size_t)c * N_ + m]));
        d = __fadd_rn(__fsub_rn(sqf[b * N_ + n], __fmul_rn(2.0f, a)), sqf[b * N_ + m]);
    }
    int rank = 0;
#pragma unroll 1
    for (int j = 0; j < CAND; ++j) {
        float dj = __shfl(d, j, 64);
        unsigned mj = (unsigned)__shfl((int)m, j, 64);
        if (lane < CAND && (dj < d || (dj == d && mj < m))) ++rank;
    }
    if (lane < CAND && rank < K_)
        idxf[grow * K_ + rank] = (float)m;
}

// K4: out[b][o][n] = leaky( s[o]*(u + max_k Yt[b][idx[n][k]][o]) + t[o] )
__global__ __launch_bounds__(256) void k_out(const float* __restrict__ x,
                                             const float* __restrict__ W,
                                             const float* __restrict__ gamma,
                                             const float* __restrict__ beta,
                                             const float* __restrict__ rmean,
                                             const float* __restrict__ rvar,
                                             const float* __restrict__ Yt,
                                             const float* __restrict__ idxf,
                                             float* __restrict__ out) {
    __shared__ float Bl[C_ * 64];
    __shared__ float xl[C_ * 64];
    __shared__ float resl[64 * 65];
    __shared__ float sl[64], tl[64];
    int tid = threadIdx.x;
    int bid = blockIdx.x;
    int b = bid >> 5;
    int n0 = (bid & 31) * 64;
    {
        int o = tid & 63, cb = tid >> 6;
#pragma unroll
        for (int j = 0; j < 16; ++j) {
            int c = cb * 16 + j;
            Bl[c * 64 + o] = W[o * 128 + 64 + c];
            xl[c * 64 + o] = x[((size_t)b * C_ + c) * N_ + n0 + o];
        }
        if (tid < 64) {
            float s = gamma[tid] / sqrtf(rvar[tid] + 1e-5f);
            sl[tid] = s;
            tl[tid] = beta[tid] - rmean[tid] * s;
        }
    }
    __syncthreads();
    int w = tid >> 6, o = tid & 63;
    for (int i = 0; i < 16; ++i) {
        int nl = w * 16 + i;
        int n = n0 + nl;
        float u = 0.f;
#pragma unroll 8
        for (int c = 0; c < C_; ++c)
            u = fmaf(Bl[c * 64 + o], xl[c * 64 + nl], u);
        const float* ip = idxf + ((size_t)b * N_ + n) * K_;
        float v = -3.4e38f;
#pragma unroll
        for (int k = 0; k < K_; ++k) {
            int mi = (int)ip[k];
            v = fmaxf(v, Yt[((size_t)b * N_ + mi) * C_ + o]);
        }
        float h = u + v;
        float val = sl[o] * h + tl[o];
        val = val > 0.f ? val : 0.2f * val;
        resl[o * 65 + nl] = val;
    }
    __syncthreads();
    {
        int nl = tid & 63, ob = tid >> 6;
#pragma unroll
        for (int j = 0; j < 16; ++j) {
            int o2 = ob * 16 + j;
            out[((size_t)b * C_ + o2) * N_ + n0 + nl] = resl[o2 * 65 + nl];
        }
    }
}

extern "C" void kernel_launch(void* const* d_in, const int* in_sizes, int n_in,
                              void* d_out, int out_size, void* d_ws, size_t ws_size,
                              hipStream_t stream) {
    const float* x     = (const float*)d_in[0];
    const float* W     = (const float*)d_in[1];
    const float* gamma = (const float*)d_in[2];
    const float* beta  = (const float*)d_in[3];
    const float* rmean = (const float*)d_in[4];
    const float* rvar  = (const float*)d_in[5];

    float* out  = (float*)d_out;                         // [16][64][2048]
    float* idxf = out + (size_t)B_ * C_ * N_;            // [16][2048][20] as floats

    char* ws       = (char*)d_ws;
    float* sqf     = (float*)ws;                         // 128 KB
    float* Yt      = (float*)(ws + 131072);              // 8 MB
    unsigned* cand = (unsigned*)(ws + 131072 + 8388608); // 3.1 MB

    k_sq     <<<B_ * N_ / 256, 256, 0, stream>>>(x, sqf);
    k_y      <<<B_ * (N_ / 64), 256, 0, stream>>>(x, W, Yt);
    k_dist   <<<B_ * (N_ / 32), 256, 0, stream>>>(x, sqf, cand);
    k_rescore<<<B_ * N_ / 4, 256, 0, stream>>>(x, sqf, cand, idxf);
    k_out    <<<B_ * (N_ / 64), 256, 0, stream>>>(x, W, gamma, beta, rmean, rvar, Yt, idxf, out);
}

// Round 5
// 613.506 us; speedup vs baseline: 2.8049x; 2.8049x over previous
//
#include <hip/hip_runtime.h>
#include <cstdint>
#include <cstddef>

#define B_ 16
#define C_ 64
#define N_ 2048
#define K_ 20
#define TM2 128
#define L 7
#define CAND 24

// K1: sqf = np.sum(xt*xt,-1) replicated bit-exactly (pairwise 8-acc tree),
// plus transposed copy xrT[b][n][c] = x[b][c][n] for scalar-path row reads.
__global__ __launch_bounds__(256) void k_sq(const float* __restrict__ x,
                                            float* __restrict__ sqf,
                                            float* __restrict__ xrT) {
    int i = blockIdx.x * 256 + threadIdx.x;   // 0..B_*N_-1
    int b = i >> 11, n = i & (N_ - 1);
    const float* xb = x + (size_t)b * C_ * N_ + n;
    float vr[C_];
#pragma unroll
    for (int c = 0; c < C_; ++c) vr[c] = xb[(size_t)c * N_];
    float p[C_];
#pragma unroll
    for (int c = 0; c < C_; ++c) p[c] = __fmul_rn(vr[c], vr[c]);
    float r[8];
#pragma unroll
    for (int k = 0; k < 8; ++k) r[k] = p[k];
#pragma unroll
    for (int ii = 8; ii < 64; ii += 8) {
#pragma unroll
        for (int k = 0; k < 8; ++k) r[k] = __fadd_rn(r[k], p[ii + k]);
    }
    float s0 = __fadd_rn(__fadd_rn(r[0], r[1]), __fadd_rn(r[2], r[3]));
    float s1 = __fadd_rn(__fadd_rn(r[4], r[5]), __fadd_rn(r[6], r[7]));
    sqf[i] = __fadd_rn(s0, s1);
    float4* dst = reinterpret_cast<float4*>(xrT + (size_t)i * C_);
#pragma unroll
    for (int q = 0; q < 16; ++q)
        dst[q] = make_float4(vr[q * 4 + 0], vr[q * 4 + 1], vr[q * 4 + 2], vr[q * 4 + 3]);
}

// K3: Yt[b][m][o] = sum_c (W[o][c] - W[o][64+c]) * x[b][c][m]
__global__ __launch_bounds__(256) void k_y(const float* __restrict__ x,
                                           const float* __restrict__ W,
                                           float* __restrict__ Yt) {
    __shared__ float Al[C_ * 64];  // [c][o]
    __shared__ float xl[C_ * 64];  // [c][m]
    int tid = threadIdx.x;
    int bid = blockIdx.x;
    int b = bid >> 5;
    int m0 = (bid & 31) * 64;
    {
        int o = tid & 63, cb = tid >> 6;
#pragma unroll
        for (int j = 0; j < 16; ++j) {
            int c = cb * 16 + j;
            Al[c * 64 + o] = W[o * 128 + c] - W[o * 128 + 64 + c];
            xl[c * 64 + o] = x[((size_t)b * C_ + c) * N_ + m0 + o];
        }
    }
    __syncthreads();
    int ml = tid & 63, og = tid >> 6;
    float acc[16];
#pragma unroll
    for (int j = 0; j < 16; ++j) acc[j] = 0.f;
#pragma unroll 4
    for (int c = 0; c < C_; ++c) {
        float xv = xl[c * 64 + ml];
        const float4* a4 = reinterpret_cast<const float4*>(&Al[c * 64 + og * 16]);
#pragma unroll
        for (int q = 0; q < 4; ++q) {
            float4 av = a4[q];
            acc[q * 4 + 0] = fmaf(av.x, xv, acc[q * 4 + 0]);
            acc[q * 4 + 1] = fmaf(av.y, xv, acc[q * 4 + 1]);
            acc[q * 4 + 2] = fmaf(av.z, xv, acc[q * 4 + 2]);
            acc[q * 4 + 3] = fmaf(av.w, xv, acc[q * 4 + 3]);
        }
    }
    float* yp = Yt + ((size_t)b * N_ + m0 + ml) * C_ + og * 16;
#pragma unroll
    for (int q = 0; q < 4; ++q) {
        reinterpret_cast<float4*>(yp)[q] =
            make_float4(acc[q * 4 + 0], acc[q * 4 + 1], acc[q * 4 + 2], acc[q * 4 + 3]);
    }
}

// K2a: fast distance pass. Rows via SGPR/SMEM (uniform loads from xrT),
// m-tile in LDS. Per-lane top-L lists in REGISTERS (all compile-time indexed).
__global__ __launch_bounds__(256) void k_dist(const float* __restrict__ x,
                                              const float* __restrict__ xrT,
                                              const float* __restrict__ sqf,
                                              unsigned* __restrict__ cand) {
    __shared__ float xt[TM2][68];   // [m][c], 272B row stride: conflict-free b128
    __shared__ float sqm[TM2];
    int tid = threadIdx.x;
    int w = tid >> 6, lane = tid & 63;
    int bid = blockIdx.x;
    int b = bid >> 6;               // 64 blocks per batch
    int n0 = (bid & 63) * 32;
    const float* xb = x + (size_t)b * C_ * N_;
    int wu = __builtin_amdgcn_readfirstlane(w);
    const float* rowbase = xrT + ((size_t)b * N_ + n0 + wu * 8) * C_;

    float rsq[8];
#pragma unroll
    for (int r = 0; r < 8; ++r) rsq[r] = sqf[b * N_ + n0 + wu * 8 + r];

    float ld[8][L], lmax[8];
    unsigned li[8][L];
#pragma unroll
    for (int r = 0; r < 8; ++r) {
        lmax[r] = 1e30f;
#pragma unroll
        for (int j = 0; j < L; ++j) { ld[r][j] = 1e30f; li[r][j] = 0u; }
    }

    for (int t = 0; t < N_ / TM2; ++t) {
        int m0 = t * TM2;
        __syncthreads();
        {   // stage m-tile
            int u = tid >> 7, ml = tid & 127;
#pragma unroll
            for (int cb = 0; cb < 8; ++cb) {
                int c = u * 32 + cb * 4;
                float4 v;
                v.x = xb[(size_t)(c + 0) * N_ + m0 + ml];
                v.y = xb[(size_t)(c + 1) * N_ + m0 + ml];
                v.z = xb[(size_t)(c + 2) * N_ + m0 + ml];
                v.w = xb[(size_t)(c + 3) * N_ + m0 + ml];
                *reinterpret_cast<float4*>(&xt[ml][c]) = v;
            }
            if (tid < TM2) sqm[tid] = sqf[b * N_ + m0 + tid];
        }
        __syncthreads();

        // opaque copy: defeat LICM hoisting of the 128 row-fragment loads
        const float* rp = rowbase;
        asm volatile("" : "+s"(rp));

        float acc[8][2];
#pragma unroll
        for (int r = 0; r < 8; ++r) { acc[r][0] = 0.f; acc[r][1] = 0.f; }
#pragma unroll 2
        for (int cc = 0; cc < 16; ++cc) {
            float4 xv0 = *reinterpret_cast<const float4*>(&xt[lane][cc * 4]);
            float4 xv1 = *reinterpret_cast<const float4*>(&xt[64 + lane][cc * 4]);
#pragma unroll
            for (int r = 0; r < 8; ++r) {
                float4 rv = *reinterpret_cast<const float4*>(rp + r * C_ + cc * 4);
                acc[r][0] = fmaf(rv.x, xv0.x, acc[r][0]);
                acc[r][0] = fmaf(rv.y, xv0.y, acc[r][0]);
                acc[r][0] = fmaf(rv.z, xv0.z, acc[r][0]);
                acc[r][0] = fmaf(rv.w, xv0.w, acc[r][0]);
                acc[r][1] = fmaf(rv.x, xv1.x, acc[r][1]);
                acc[r][1] = fmaf(rv.y, xv1.y, acc[r][1]);
                acc[r][1] = fmaf(rv.z, xv1.z, acc[r][1]);
                acc[r][1] = fmaf(rv.w, xv1.w, acc[r][1]);
            }
        }
#pragma unroll
        for (int s = 0; s < 2; ++s) {
            float sm = sqm[s * 64 + lane];
            int m = m0 + s * 64 + lane;
#pragma unroll
            for (int r = 0; r < 8; ++r) {
                float d = (rsq[r] + sm) - 2.f * acc[r][s];
                if (d < lmax[r]) {
                    bool done = false;
#pragma unroll
                    for (int j = 0; j < L; ++j) {
                        bool hit = (!done) && (ld[r][j] == lmax[r]);
                        if (hit) { ld[r][j] = d; li[r][j] = (unsigned)m; done = true; }
                    }
                    float mx = ld[r][0];
#pragma unroll
                    for (int j = 1; j < L; ++j) mx = fmaxf(mx, ld[r][j]);
                    lmax[r] = mx;
                }
            }
        }
    }

    // extraction: CAND rounds of wave-min + knockout, per row.
    // r loop FULLY UNROLLED so ld/li indices stay compile-time (rule #20).
#pragma unroll
    for (int r = 0; r < 8; ++r) {
        size_t grow = (size_t)b * N_ + n0 + wu * 8 + r;
#pragma unroll 1
        for (int it = 0; it < CAND; ++it) {
            float v = ld[r][0];
#pragma unroll
            for (int j = 1; j < L; ++j) v = fminf(v, ld[r][j]);
            float wv = v;
#pragma unroll
            for (int d2 = 1; d2 < 64; d2 <<= 1)
                wv = fminf(wv, __shfl_xor(wv, d2, 64));
            unsigned long long bal = __ballot(v == wv);
            int owner = __ffsll((unsigned long long)bal) - 1;
            if (lane == owner) {
                bool done = false;
                unsigned mi = 0;
#pragma unroll
                for (int j = 0; j < L; ++j) {
                    bool hit = (!done) && (ld[r][j] == wv);
                    if (hit) { mi = li[r][j]; ld[r][j] = 1e30f; done = true; }
                }
                cand[grow * CAND + it] = mi;
            }
        }
    }
}

// K2b: exact numpy-f32 rescore (sequential c, separate mul/add) + stable rank.
// Uses contiguous xrT rows: identical values & order to round-3's proven form.
__global__ __launch_bounds__(256) void k_rescore(const float* __restrict__ xrT,
                                                 const float* __restrict__ sqf,
                                                 const unsigned* __restrict__ cand,
                                                 float* __restrict__ idxf) {
    int tid = threadIdx.x;
    int w = tid >> 6, lane = tid & 63;
    size_t grow = (size_t)blockIdx.x * 4 + w;   // 0..32767
    int b = (int)(grow >> 11), n = (int)(grow & (N_ - 1));
    const float* xr = xrT + (size_t)b * N_ * C_;
    const float* xn = xr + (size_t)n * C_;
    float d = 0.f;
    unsigned m = 0xFFFFFFFFu;
    if (lane < CAND) {
        m = cand[grow * CAND + lane];
        const float* xm = xr + (size_t)m * C_;
        float a = 0.f;
#pragma unroll 8
        for (int c = 0; c < C_; ++c)
            a = __fadd_rn(a, __fmul_rn(xn[c], xm[c]));
        d = __fadd_rn(__fsub_rn(sqf[b * N_ + n], __fmul_rn(2.0f, a)), sqf[b * N_ + m]);
    }
    int rank = 0;
#pragma unroll 1
    for (int j = 0; j < CAND; ++j) {
        float dj = __shfl(d, j, 64);
        unsigned mj = (unsigned)__shfl((int)m, j, 64);
        if (lane < CAND && (dj < d || (dj == d && mj < m))) ++rank;
    }
    if (lane < CAND && rank < K_)
        idxf[grow * K_ + rank] = (float)m;
}

// K4: out[b][o][n] = leaky( s[o]*(u + max_k Yt[b][idx[n][k]][o]) + t[o] )
__global__ __launch_bounds__(256) void k_out(const float* __restrict__ x,
                                             const float* __restrict__ W,
                                             const float* __restrict__ gamma,
                                             const float* __restrict__ beta,
                                             const float* __restrict__ rmean,
                                             const float* __restrict__ rvar,
                                             const float* __restrict__ Yt,
                                             const float* __restrict__ idxf,
                                             float* __restrict__ out) {
    __shared__ float Bl[C_ * 64];
    __shared__ float xl[C_ * 64];
    __shared__ float resl[64 * 65];
    __shared__ float sl[64], tl[64];
    int tid = threadIdx.x;
    int bid = blockIdx.x;
    int b = bid >> 5;
    int n0 = (bid & 31) * 64;
    {
        int o = tid & 63, cb = tid >> 6;
#pragma unroll
        for (int j = 0; j < 16; ++j) {
            int c = cb * 16 + j;
            Bl[c * 64 + o] = W[o * 128 + 64 + c];
            xl[c * 64 + o] = x[((size_t)b * C_ + c) * N_ + n0 + o];
        }
        if (tid < 64) {
            float s = gamma[tid] / sqrtf(rvar[tid] + 1e-5f);
            sl[tid] = s;
            tl[tid] = beta[tid] - rmean[tid] * s;
        }
    }
    __syncthreads();
    int w = tid >> 6, o = tid & 63;
    for (int i = 0; i < 16; ++i) {
        int nl = w * 16 + i;
        int n = n0 + nl;
        float u = 0.f;
#pragma unroll 8
        for (int c = 0; c < C_; ++c)
            u = fmaf(Bl[c * 64 + o], xl[c * 64 + nl], u);
        const float* ip = idxf + ((size_t)b * N_ + n) * K_;
        float v = -3.4e38f;
#pragma unroll
        for (int k = 0; k < K_; ++k) {
            int mi = (int)ip[k];
            v = fmaxf(v, Yt[((size_t)b * N_ + mi) * C_ + o]);
        }
        float h = u + v;
        float val = sl[o] * h + tl[o];
        val = val > 0.f ? val : 0.2f * val;
        resl[o * 65 + nl] = val;
    }
    __syncthreads();
    {
        int nl = tid & 63, ob = tid >> 6;
#pragma unroll
        for (int j = 0; j < 16; ++j) {
            int o2 = ob * 16 + j;
            out[((size_t)b * C_ + o2) * N_ + n0 + nl] = resl[o2 * 65 + nl];
        }
    }
}

extern "C" void kernel_launch(void* const* d_in, const int* in_sizes, int n_in,
                              void* d_out, int out_size, void* d_ws, size_t ws_size,
                              hipStream_t stream) {
    const float* x     = (const float*)d_in[0];
    const float* W     = (const float*)d_in[1];
    const float* gamma = (const float*)d_in[2];
    const float* beta  = (const float*)d_in[3];
    const float* rmean = (const float*)d_in[4];
    const float* rvar  = (const float*)d_in[5];

    float* out  = (float*)d_out;                         // [16][64][2048]
    float* idxf = out + (size_t)B_ * C_ * N_;            // [16][2048][20] as floats

    char* ws       = (char*)d_ws;
    float* sqf     = (float*)ws;                         // 128 KB
    unsigned* cand = (unsigned*)(ws + 131072);           // 3.1 MB
    float* xrT     = (float*)(ws + 131072 + 3145728);    // 8 MB
    float* Yt      = xrT;  // aliases xrT: xrT dead after k_rescore, Yt born at k_y

    k_sq     <<<B_ * N_ / 256, 256, 0, stream>>>(x, sqf, xrT);
    k_dist   <<<B_ * (N_ / 32), 256, 0, stream>>>(x, xrT, sqf, cand);
    k_rescore<<<B_ * N_ / 4, 256, 0, stream>>>(xrT, sqf, cand, idxf);
    k_y      <<<B_ * (N_ / 64), 256, 0, stream>>>(x, W, Yt);
    k_out    <<<B_ * (N_ / 64), 256, 0, stream>>>(x, W, gamma, beta, rmean, rvar, Yt, idxf, out);
}

// Round 6
// 358.404 us; speedup vs baseline: 4.8013x; 1.7118x over previous
//
#include <hip/hip_runtime.h>
#include <cstdint>
#include <cstddef>

#define B_ 16
#define C_ 64
#define N_ 2048
#define K_ 20
#define TM2 128
#define L 7
#define CAND 24

__device__ __forceinline__ unsigned umin_(unsigned a, unsigned b) { return a < b ? a : b; }
__device__ __forceinline__ unsigned umax_(unsigned a, unsigned b) { return a > b ? a : b; }

// K1: sqf = np.sum(xt*xt,-1) replicated bit-exactly (pairwise 8-acc tree),
// plus transposed copy xrT[b][n][c] = x[b][c][n] for k_rescore's contiguous rows.
__global__ __launch_bounds__(128) void k_sq(const float* __restrict__ x,
                                            float* __restrict__ sqf,
                                            float* __restrict__ xrT) {
    int i = blockIdx.x * 128 + threadIdx.x;   // 0..B_*N_-1
    int b = i >> 11, n = i & (N_ - 1);
    const float* xb = x + (size_t)b * C_ * N_ + n;
    float vr[C_];
#pragma unroll
    for (int c = 0; c < C_; ++c) vr[c] = xb[(size_t)c * N_];
    float p[C_];
#pragma unroll
    for (int c = 0; c < C_; ++c) p[c] = __fmul_rn(vr[c], vr[c]);
    float r[8];
#pragma unroll
    for (int k = 0; k < 8; ++k) r[k] = p[k];
#pragma unroll
    for (int ii = 8; ii < 64; ii += 8) {
#pragma unroll
        for (int k = 0; k < 8; ++k) r[k] = __fadd_rn(r[k], p[ii + k]);
    }
    float s0 = __fadd_rn(__fadd_rn(r[0], r[1]), __fadd_rn(r[2], r[3]));
    float s1 = __fadd_rn(__fadd_rn(r[4], r[5]), __fadd_rn(r[6], r[7]));
    sqf[i] = __fadd_rn(s0, s1);
    float4* dst = reinterpret_cast<float4*>(xrT + (size_t)i * C_);
#pragma unroll
    for (int q = 0; q < 16; ++q)
        dst[q] = make_float4(vr[q * 4 + 0], vr[q * 4 + 1], vr[q * 4 + 2], vr[q * 4 + 3]);
}

// K3: Yt[b][m][o] = sum_c (W[o][c] - W[o][64+c]) * x[b][c][m]
__global__ __launch_bounds__(256) void k_y(const float* __restrict__ x,
                                           const float* __restrict__ W,
                                           float* __restrict__ Yt) {
    __shared__ float Al[C_ * 64];  // [c][o]
    __shared__ float xl[C_ * 64];  // [c][m]
    int tid = threadIdx.x;
    int bid = blockIdx.x;
    int b = bid >> 5;
    int m0 = (bid & 31) * 64;
    {
        int o = tid & 63, cb = tid >> 6;
#pragma unroll
        for (int j = 0; j < 16; ++j) {
            int c = cb * 16 + j;
            Al[c * 64 + o] = W[o * 128 + c] - W[o * 128 + 64 + c];
            xl[c * 64 + o] = x[((size_t)b * C_ + c) * N_ + m0 + o];
        }
    }
    __syncthreads();
    int ml = tid & 63, og = tid >> 6;
    float acc[16];
#pragma unroll
    for (int j = 0; j < 16; ++j) acc[j] = 0.f;
#pragma unroll 4
    for (int c = 0; c < C_; ++c) {
        float xv = xl[c * 64 + ml];
        const float4* a4 = reinterpret_cast<const float4*>(&Al[c * 64 + og * 16]);
#pragma unroll
        for (int q = 0; q < 4; ++q) {
            float4 av = a4[q];
            acc[q * 4 + 0] = fmaf(av.x, xv, acc[q * 4 + 0]);
            acc[q * 4 + 1] = fmaf(av.y, xv, acc[q * 4 + 1]);
            acc[q * 4 + 2] = fmaf(av.z, xv, acc[q * 4 + 2]);
            acc[q * 4 + 3] = fmaf(av.w, xv, acc[q * 4 + 3]);
        }
    }
    float* yp = Yt + ((size_t)b * N_ + m0 + ml) * C_ + og * 16;
#pragma unroll
    for (int q = 0; q < 4; ++q) {
        reinterpret_cast<float4*>(yp)[q] =
            make_float4(acc[q * 4 + 0], acc[q * 4 + 1], acc[q * 4 + 2], acc[q * 4 + 3]);
    }
}

// K2a: fast distance pass. 64 rows/block (8 waves x 8 rows), rows in LDS read
// via wave-uniform broadcast b128; m-tile in LDS; per-lane sorted top-L of
// packed u32 keys (quantized dist | m). Extraction: 24 wave-min rounds.
__global__ __launch_bounds__(512, 4) void k_dist(const float* __restrict__ x,
                                                 const float* __restrict__ sqf,
                                                 unsigned* __restrict__ cand) {
    __shared__ float xt[TM2][66];     // stride 264B: 2-way on b128 (free)
    __shared__ float rowsl[64][66];
    int tid = threadIdx.x;
    int w = tid >> 6, lane = tid & 63;
    int bid = blockIdx.x;
    int b = bid >> 5;                 // 32 blocks per batch
    int n0 = (bid & 31) * 64;
    const float* xb = x + (size_t)b * C_ * N_;

    {   // stage 64 rows: wave w stages c = w*8 .. w*8+7 (coalesced per c)
#pragma unroll
        for (int j = 0; j < 8; ++j) {
            int c = w * 8 + j;
            rowsl[lane][c] = xb[(size_t)c * N_ + n0 + lane];
        }
    }
    float rsq[8];
#pragma unroll
    for (int r = 0; r < 8; ++r) rsq[r] = sqf[b * N_ + n0 + w * 8 + r];

    unsigned list[8][L];
#pragma unroll
    for (int r = 0; r < 8; ++r)
#pragma unroll
        for (int j = 0; j < L; ++j) list[r][j] = 0xFFFFFFFFu;

    for (int t = 0; t < N_ / TM2; ++t) {
        int m0 = t * TM2;
        __syncthreads();
        {   // stage m-tile (coalesced per c)
            int u = tid >> 7, ml = tid & 127;
#pragma unroll
            for (int cb = 0; cb < 4; ++cb) {
                int c = u * 16 + cb * 4;
                float4 v;
                v.x = xb[(size_t)(c + 0) * N_ + m0 + ml];
                v.y = xb[(size_t)(c + 1) * N_ + m0 + ml];
                v.z = xb[(size_t)(c + 2) * N_ + m0 + ml];
                v.w = xb[(size_t)(c + 3) * N_ + m0 + ml];
                *reinterpret_cast<float4*>(&xt[ml][c]) = v;
            }
        }
        __syncthreads();

        // opaque row index: stop LICM from hoisting 128 float4 row reads
        int rb = w * 8;
        asm volatile("" : "+v"(rb));

        float acc[8][2];
#pragma unroll
        for (int r = 0; r < 8; ++r) { acc[r][0] = 0.f; acc[r][1] = 0.f; }
#pragma unroll 2
        for (int cc = 0; cc < 16; ++cc) {
            float4 xv0 = *reinterpret_cast<const float4*>(&xt[lane][cc * 4]);
            float4 xv1 = *reinterpret_cast<const float4*>(&xt[64 + lane][cc * 4]);
#pragma unroll
            for (int r = 0; r < 8; ++r) {
                float4 rv = *reinterpret_cast<const float4*>(&rowsl[rb + r][cc * 4]);
                acc[r][0] = fmaf(rv.x, xv0.x, acc[r][0]);
                acc[r][0] = fmaf(rv.y, xv0.y, acc[r][0]);
                acc[r][0] = fmaf(rv.z, xv0.z, acc[r][0]);
                acc[r][0] = fmaf(rv.w, xv0.w, acc[r][0]);
                acc[r][1] = fmaf(rv.x, xv1.x, acc[r][1]);
                acc[r][1] = fmaf(rv.y, xv1.y, acc[r][1]);
                acc[r][1] = fmaf(rv.z, xv1.z, acc[r][1]);
                acc[r][1] = fmaf(rv.w, xv1.w, acc[r][1]);
            }
        }
        float sm0 = sqf[b * N_ + m0 + lane];
        float sm1 = sqf[b * N_ + m0 + 64 + lane];
#pragma unroll
        for (int s = 0; s < 2; ++s) {
            float sm = s ? sm1 : sm0;
            unsigned m = (unsigned)(m0 + s * 64 + lane);
#pragma unroll
            for (int r = 0; r < 8; ++r) {
                float d = (rsq[r] + sm) - 2.f * acc[r][s];
                unsigned ub = __float_as_uint(d);
                unsigned mono = (ub & 0x80000000u) ? ~ub : (ub | 0x80000000u);
                unsigned key = (mono & 0xFFFFF800u) | m;
                // branchless sorted insert (ascending, list[0]=min)
#pragma unroll
                for (int j = L - 1; j > 0; --j)
                    list[r][j] = umin_(list[r][j], umax_(list[r][j - 1], key));
                list[r][0] = umin_(list[r][0], key);
            }
        }
    }

    // extraction: per row, 24 rounds of wave-min over sorted heads.
    // keys are unique (low 11 bits = m, m%64 = lane) -> exactly one owner.
#pragma unroll
    for (int r = 0; r < 8; ++r) {
        size_t grow = (size_t)b * N_ + n0 + w * 8 + r;
        unsigned myex = 0u;
#pragma unroll 1
        for (int it = 0; it < CAND; ++it) {
            unsigned head = list[r][0];
            unsigned wv = head;
#pragma unroll
            for (int d2 = 1; d2 < 64; d2 <<= 1)
                wv = umin_(wv, (unsigned)__shfl_xor((int)wv, d2, 64));
            bool own = (head == wv);
#pragma unroll
            for (int j = 0; j < L - 1; ++j)
                list[r][j] = own ? list[r][j + 1] : list[r][j];
            list[r][L - 1] = own ? 0xFFFFFFFFu : list[r][L - 1];
            myex = (lane == it) ? (wv & 2047u) : myex;
        }
        if (lane < CAND) cand[grow * CAND + lane] = myex;
    }
}

// K2b: exact numpy-f32 rescore (sequential c, separate mul/add) + stable rank.
__global__ __launch_bounds__(256) void k_rescore(const float* __restrict__ xrT,
                                                 const float* __restrict__ sqf,
                                                 const unsigned* __restrict__ cand,
                                                 float* __restrict__ idxf) {
    int tid = threadIdx.x;
    int w = tid >> 6, lane = tid & 63;
    size_t grow = (size_t)blockIdx.x * 4 + w;   // 0..32767
    int b = (int)(grow >> 11), n = (int)(grow & (N_ - 1));
    const float* xr = xrT + (size_t)b * N_ * C_;
    const float* xn = xr + (size_t)n * C_;
    float d = 0.f;
    unsigned m = 0xFFFFFFFFu;
    if (lane < CAND) {
        m = cand[grow * CAND + lane];
        const float* xm = xr + (size_t)m * C_;
        float a = 0.f;
#pragma unroll 8
        for (int c = 0; c < C_; ++c)
            a = __fadd_rn(a, __fmul_rn(xn[c], xm[c]));
        d = __fadd_rn(__fsub_rn(sqf[b * N_ + n], __fmul_rn(2.0f, a)), sqf[b * N_ + m]);
    }
    int rank = 0;
#pragma unroll 1
    for (int j = 0; j < CAND; ++j) {
        float dj = __shfl(d, j, 64);
        unsigned mj = (unsigned)__shfl((int)m, j, 64);
        if (lane < CAND && (dj < d || (dj == d && mj < m))) ++rank;
    }
    if (lane < CAND && rank < K_)
        idxf[grow * K_ + rank] = (float)m;
}

// K4: out[b][o][n] = leaky( s[o]*(u + max_k Yt[b][idx[n][k]][o]) + t[o] )
__global__ __launch_bounds__(256) void k_out(const float* __restrict__ x,
                                             const float* __restrict__ W,
                                             const float* __restrict__ gamma,
                                             const float* __restrict__ beta,
                                             const float* __restrict__ rmean,
                                             const float* __restrict__ rvar,
                                             const float* __restrict__ Yt,
                                             const float* __restrict__ idxf,
                                             float* __restrict__ out) {
    __shared__ float Bl[C_ * 64];
    __shared__ float xl[C_ * 64];
    __shared__ float resl[64 * 65];
    __shared__ float sl[64], tl[64];
    int tid = threadIdx.x;
    int bid = blockIdx.x;
    int b = bid >> 5;
    int n0 = (bid & 31) * 64;
    {
        int o = tid & 63, cb = tid >> 6;
#pragma unroll
        for (int j = 0; j < 16; ++j) {
            int c = cb * 16 + j;
            Bl[c * 64 + o] = W[o * 128 + 64 + c];
            xl[c * 64 + o] = x[((size_t)b * C_ + c) * N_ + n0 + o];
        }
        if (tid < 64) {
            float s = gamma[tid] / sqrtf(rvar[tid] + 1e-5f);
            sl[tid] = s;
            tl[tid] = beta[tid] - rmean[tid] * s;
        }
    }
    __syncthreads();
    int w = tid >> 6, o = tid & 63;
    for (int i = 0; i < 16; ++i) {
        int nl = w * 16 + i;
        int n = n0 + nl;
        float u = 0.f;
#pragma unroll 8
        for (int c = 0; c < C_; ++c)
            u = fmaf(Bl[c * 64 + o], xl[c * 64 + nl], u);
        const float* ip = idxf + ((size_t)b * N_ + n) * K_;
        float v = -3.4e38f;
#pragma unroll
        for (int k = 0; k < K_; ++k) {
            int mi = (int)ip[k];
            v = fmaxf(v, Yt[((size_t)b * N_ + mi) * C_ + o]);
        }
        float h = u + v;
        float val = sl[o] * h + tl[o];
        val = val > 0.f ? val : 0.2f * val;
        resl[o * 65 + nl] = val;
    }
    __syncthreads();
    {
        int nl = tid & 63, ob = tid >> 6;
#pragma unroll
        for (int j = 0; j < 16; ++j) {
            int o2 = ob * 16 + j;
            out[((size_t)b * C_ + o2) * N_ + n0 + nl] = resl[o2 * 65 + nl];
        }
    }
}

extern "C" void kernel_launch(void* const* d_in, const int* in_sizes, int n_in,
                              void* d_out, int out_size, void* d_ws, size_t ws_size,
                              hipStream_t stream) {
    const float* x     = (const float*)d_in[0];
    const float* W     = (const float*)d_in[1];
    const float* gamma = (const float*)d_in[2];
    const float* beta  = (const float*)d_in[3];
    const float* rmean = (const float*)d_in[4];
    const float* rvar  = (const float*)d_in[5];

    float* out  = (float*)d_out;                         // [16][64][2048]
    float* idxf = out + (size_t)B_ * C_ * N_;            // [16][2048][20] as floats

    char* ws       = (char*)d_ws;
    float* sqf     = (float*)ws;                         // 128 KB
    unsigned* cand = (unsigned*)(ws + 131072);           // 3.1 MB
    float* xrT     = (float*)(ws + 131072 + 3145728);    // 8 MB
    float* Yt      = xrT;  // aliases xrT: xrT dead after k_rescore, Yt born at k_y

    k_sq     <<<B_ * N_ / 128, 128, 0, stream>>>(x, sqf, xrT);
    k_dist   <<<B_ * (N_ / 64), 512, 0, stream>>>(x, sqf, cand);
    k_rescore<<<B_ * N_ / 4, 256, 0, stream>>>(xrT, sqf, cand, idxf);
    k_y      <<<B_ * (N_ / 64), 256, 0, stream>>>(x, W, Yt);
    k_out    <<<B_ * (N_ / 64), 256, 0, stream>>>(x, W, gamma, beta, rmean, rvar, Yt, idxf, out);
}